// Round 1
// baseline (24.946 us; speedup 1.0000x reference)
//
#include <hip/hip_runtime.h>

#define BATCH 128
#define NOUT 2048
#define NIN 512
#define BT 16      // batch tile
#define IT 16      // out-feature tile
#define LCH 128    // l-chunk
#define LSTR 132   // padded LDS stride (floats): 132%32=4 -> <=2-way aliasing (free)

__global__ __launch_bounds__(256)
void lse_kernel(const float* __restrict__ x, const float* __restrict__ w,
                float* __restrict__ out) {
    __shared__ float lx[BT][LSTR];
    __shared__ float lw[IT][LSTR];

    const int tid = threadIdx.x;
    const int bblk = blockIdx.x & 7;     // 128/16 = 8 batch blocks
    const int iblk = blockIdx.x >> 3;    // 2048/16 = 128 i blocks
    const int b0 = bblk * BT;
    const int i0 = iblk * IT;
    const int tb = tid >> 4;             // 0..15 batch within tile
    const int ti = tid & 15;             // 0..15 i within tile

    const float LOG2E = 1.4426950408889634f;

    float a0 = 0.f, a1 = 0.f, a2 = 0.f, a3 = 0.f;

    for (int l0 = 0; l0 < NIN; l0 += LCH) {
        // Stage x-tile (scaled by log2e) and w-tile into LDS.
        // Each tile: 16 rows x 128 cols = 512 float4s; 256 threads -> 2 float4s each.
        #pragma unroll
        for (int q = 0; q < 2; ++q) {
            const int f4 = tid + q * 256;        // 0..511
            const int r  = f4 >> 5;              // 32 float4 per row
            const int c  = (f4 & 31) << 2;
            float4 xv = *(const float4*)&x[(b0 + r) * NIN + l0 + c];
            xv.x *= LOG2E; xv.y *= LOG2E; xv.z *= LOG2E; xv.w *= LOG2E;
            *(float4*)&lx[r][c] = xv;
            float4 wv = *(const float4*)&w[(i0 + r) * NIN + l0 + c];
            *(float4*)&lw[r][c] = wv;
        }
        __syncthreads();

        #pragma unroll 8
        for (int c = 0; c < LCH; c += 4) {
            const float4 wv = *(const float4*)&lw[ti][c];
            const float4 xv = *(const float4*)&lx[tb][c];
            a0 += __builtin_amdgcn_exp2f(wv.x * xv.x);
            a1 += __builtin_amdgcn_exp2f(wv.y * xv.y);
            a2 += __builtin_amdgcn_exp2f(wv.z * xv.z);
            a3 += __builtin_amdgcn_exp2f(wv.w * xv.w);
        }
        __syncthreads();
    }

    const float S = (a0 + a1) + (a2 + a3);
    const int b = b0 + tb;
    const int i = i0 + ti;
    // ln(S) = log2(S) * ln(2)
    out[b * NOUT + i] = __builtin_amdgcn_logf(S) * 0.6931471805599453f;
}

extern "C" void kernel_launch(void* const* d_in, const int* in_sizes, int n_in,
                              void* d_out, int out_size, void* d_ws, size_t ws_size,
                              hipStream_t stream) {
    const float* x = (const float*)d_in[0];      // [128, 512]
    const float* w = (const float*)d_in[1];      // [2048, 512]
    float* out = (float*)d_out;                  // [128, 2048]
    (void)in_sizes; (void)n_in; (void)out_size; (void)d_ws; (void)ws_size;

    dim3 grid(1024);   // (2048/16) * (128/16)
    dim3 block(256);
    lse_kernel<<<grid, block, 0, stream>>>(x, w, out);
}